// Round 5
// baseline (409.393 us; speedup 1.0000x reference)
//
#include <hip/hip_runtime.h>
#include <hip/hip_bf16.h>
#include <type_traits>

// Problem constants
#define DIMN   2048
#define NH     16
#define NKVH   4
#define HD     128
#define KVD    512        // NKVH*HD
#define NQKV   3072       // DIMN + 2*KVD
#define BATCH  2
#define SEQ    2048
#define MROWS  4096       // BATCH*SEQ
#define VOFF   2560       // DIMN + KVD: v offset inside qkv row

typedef __attribute__((ext_vector_type(8))) __bf16 bf16x8;
typedef __attribute__((ext_vector_type(4))) float floatx4;

#define BIG_NEG (-1.0e30f)

// hardware RTNE f32->bf16 (v_cvt_pk_bf16_f32)
__device__ __forceinline__ short bf16rn(float f) {
  union { __bf16 h; short s; } u;
  u.h = (__bf16)f;
  return u.s;
}
__device__ __forceinline__ float bf2f(short s) {
  union { unsigned u; float f; } v;
  v.u = ((unsigned)(unsigned short)s) << 16;
  return v.f;
}

// async 16B global -> LDS. LDS dest = wave-uniform base + lane*16 B;
// one instruction covers 64 lanes * 16 B = 512 shorts.
__device__ __forceinline__ void async_cp16(const short* g, short* l) {
  __builtin_amdgcn_global_load_lds(
      (const __attribute__((address_space(1))) unsigned int*)g,
      (__attribute__((address_space(3))) unsigned int*)l, 16, 0, 0);
}

// ---------------------------------------------------------------- f32 -> bf16
__global__ void f32_to_bf16_kern(const float* __restrict__ in,
                                 short* __restrict__ out, int n8) {
  int i = blockIdx.x * blockDim.x + threadIdx.x;
  if (i >= n8) return;
  float4 a = ((const float4*)in)[i * 2];
  float4 b = ((const float4*)in)[i * 2 + 1];
  short r[8];
  r[0] = bf16rn(a.x); r[1] = bf16rn(a.y); r[2] = bf16rn(a.z); r[3] = bf16rn(a.w);
  r[4] = bf16rn(b.x); r[5] = bf16rn(b.y); r[6] = bf16rn(b.z); r[7] = bf16rn(b.w);
  ((uint4*)out)[i] = *(const uint4*)r;
}

// --------------------------------------------------- C[M][N] = A[M][K] B[N][K]^T
// 128x128 tile, BK=32, double-buffered global_load_lds staging, one barrier per
// K-iter. XOR-swizzled LDS (stored chunk = logical ^ (row&3)). OUT: float or
// bf16 (short) epilogue.
template <typename OUT>
__global__ __launch_bounds__(256) void gemm_bt_as(const short* __restrict__ A,
                                                  const short* __restrict__ Bw,
                                                  OUT* __restrict__ C,
                                                  int N, int K) {
  __shared__ __align__(16) short As[2][128 * 32];
  __shared__ __align__(16) short Bs[2][128 * 32];
  const int t = threadIdx.x;
  const int lane = t & 63, wave = t >> 6;
  const int lrow = lane & 15, quad = lane >> 4;
  const int wr = wave >> 1, wc = wave & 1;
  const int m0 = blockIdx.y * 128, n0 = blockIdx.x * 128;

  const short* pa[2];
  const short* pb[2];
  int wi2[2];
#pragma unroll
  for (int i = 0; i < 2; i++) {
    int wi = wave * 2 + i;
    int row = wi * 16 + (lane >> 2);
    int col = ((lane & 3) ^ (row & 3)) * 8;
    pa[i] = A + (size_t)(m0 + row) * K + col;
    pb[i] = Bw + (size_t)(n0 + row) * K + col;
    wi2[i] = wi;
  }

  floatx4 acc[4][4] = {};
  const int iters = K >> 5;

#pragma unroll
  for (int i = 0; i < 2; i++) {
    async_cp16(pa[i], &As[0][wi2[i] * 512]);
    async_cp16(pb[i], &Bs[0][wi2[i] * 512]);
  }

  for (int it = 0; it < iters; it++) {
    const int cur = it & 1;
    __syncthreads();   // drains stage(it); prior iter's reads of buf[cur^1] done

    if (it + 1 < iters) {
      const int off = (it + 1) * 32;
#pragma unroll
      for (int i = 0; i < 2; i++) {
        async_cp16(pa[i] + off, &As[cur ^ 1][wi2[i] * 512]);
        async_cp16(pb[i] + off, &Bs[cur ^ 1][wi2[i] * 512]);
      }
    }

    bf16x8 af[4], bfr[4];
#pragma unroll
    for (int mt = 0; mt < 4; mt++) {
      int row = wr * 64 + mt * 16 + lrow;
      af[mt] = *(const bf16x8*)&As[cur][row * 32 + (quad ^ (lrow & 3)) * 8];
    }
#pragma unroll
    for (int nt = 0; nt < 4; nt++) {
      int row = wc * 64 + nt * 16 + lrow;
      bfr[nt] = *(const bf16x8*)&Bs[cur][row * 32 + (quad ^ (lrow & 3)) * 8];
    }
#pragma unroll
    for (int mt = 0; mt < 4; mt++)
#pragma unroll
      for (int nt = 0; nt < 4; nt++)
        acc[mt][nt] = __builtin_amdgcn_mfma_f32_16x16x32_bf16(af[mt], bfr[nt],
                                                              acc[mt][nt], 0, 0, 0);
  }

#pragma unroll
  for (int mt = 0; mt < 4; mt++)
#pragma unroll
    for (int nt = 0; nt < 4; nt++) {
      int row = m0 + wr * 64 + mt * 16 + quad * 4;
      int col = n0 + wc * 64 + nt * 16 + lrow;
#pragma unroll
      for (int r = 0; r < 4; r++) {
        if constexpr (std::is_same<OUT, short>::value)
          C[(size_t)(row + r) * N + col] = bf16rn(acc[mt][nt][r]);
        else
          C[(size_t)(row + r) * N + col] = acc[mt][nt][r];
      }
    }
}

// ---------------------------------------------------- rope cos/sin table (once)
// tab[pos*64 + ln] = (cos, sin) of pos * 10000^(-ln/64). Bit-identical math to
// the previous per-element computation, done SEQ*64 times instead of 40x that.
__global__ void rope_tab_kern(float2* __restrict__ tab) {
  int i = blockIdx.x * 256 + threadIdx.x;
  int pos = i >> 6, ln = i & 63;
  float fr = (float)pos * exp2f((float)ln * -0.20762050593045935f);
  float s, c;
  sincosf(fr, &s, &c);
  tab[i] = make_float2(c, s);
}

// -------------------------------------------- per-(row,head): RMSNorm+RoPE+gain
// qkv bf16. one wave per (row, slot): slots 0..15 = q heads, 16..19 = k heads
__global__ __launch_bounds__(256) void rms_rope_kern(const short* __restrict__ qkv,
                                                     const float* __restrict__ gain,
                                                     const float2* __restrict__ tab,
                                                     short* __restrict__ qb,
                                                     short* __restrict__ kb) {
  const int t = threadIdx.x;
  const int lane = t & 63, wave = t >> 6;
  const int gw = blockIdx.x * 4 + wave;
  const int row = gw / 20, slot = gw - row * 20;
  const int pos = row & (SEQ - 1);

  const short* src = (slot < 16) ? qkv + (size_t)row * NQKV + slot * HD
                                 : qkv + (size_t)row * NQKV + DIMN + (slot - 16) * HD;
  float x1 = bf2f(src[lane]), x2 = bf2f(src[lane + 64]);

  float ss = x1 * x1 + x2 * x2;
#pragma unroll
  for (int off = 32; off > 0; off >>= 1) ss += __shfl_xor(ss, off);
  float inv = rsqrtf(ss * (1.0f / 128.0f) + 1.1920928955078125e-7f);
  x1 *= inv; x2 *= inv;
  float2 cs = tab[pos * 64 + lane];
  float c = cs.x, s = cs.y;
  float y1 = x1 * c + x2 * s;
  float y2 = x2 * c - x1 * s;
  if (slot < 16) {
    // q_gain * 1/sqrt(HD) * log2(e): softmax then uses exp2 directly
    float g = gain[slot] * 0.12751744459132754f;
    y1 *= g; y2 *= g;
  }
  short o1 = bf16rn(y1), o2 = bf16rn(y2);
  if (slot < 16) { short* d = qb + (size_t)row * DIMN + slot * HD;        d[lane] = o1; d[lane + 64] = o2; }
  else           { short* d = kb + (size_t)row * KVD + (slot - 16) * HD;  d[lane] = o1; d[lane + 64] = o2; }
}

// ------------------------------------- v transpose: qkv bf16 [t][d] -> vT bf16 [d][t]
__global__ __launch_bounds__(256) void vT_kern(const short* __restrict__ qkv,
                                               short* __restrict__ vT) {
  __shared__ short L[64 * 68];
  const int t0 = blockIdx.x * 64, d0 = blockIdx.y * 64;
  const int b = blockIdx.z >> 2, kvh = blockIdx.z & 3;
  const int t = threadIdx.x;

#pragma unroll
  for (int p = 0; p < 4; p++) {
    int tt = p * 16 + (t >> 4);
    int dd = (t & 15) * 4;
    ushort4 v = *(const ushort4*)(qkv + (size_t)(b * SEQ + t0 + tt) * NQKV + VOFF + kvh * HD + d0 + dd);
    *(ushort4*)&L[tt * 68 + dd] = v;
  }
  __syncthreads();

  const int dl = t >> 2;
  const int tc = (t & 3) * 16;
  short tmp[16];
#pragma unroll
  for (int j = 0; j < 16; j++) tmp[j] = L[(tc + j) * 68 + dl];
  size_t obase = (size_t)((b * NKVH + kvh) * HD + d0 + dl) * SEQ + t0 + tc;
  *(uint4*)(vT + obase)     = ((const uint4*)tmp)[0];
  *(uint4*)(vT + obase + 8) = ((const uint4*)tmp)[1];
}

// ------------------------------------------------------- causal flash attention
// ROUND 5: occupancy via BIGGER BLOCKS, sync structure = proven R1 pattern
// (double-buffered K, V staged at tile start + drained at barrier-2 after a
// full compute phase, overwrite always one barrier-epoch after last read).
// 8 waves (512 thr), 128 Q-rows x 1 head per block. LDS = Ks[2] 32K + Vs 16K
// + Ps 16K = 64 KB -> 2 blocks/CU x 8 waves = 16 waves/CU (2x R1's 8), VGPR
// ~124 -> 4 waves/SIMD feasible. K/V staging amortized over 2x waves.
// Grid (16 qt, 32 bh) = 512 blocks, longest-first (qt = 15 - bx): greedy
// backfill pairs long+short blocks -> near-uniform CU makespan.
__global__ __launch_bounds__(512) void attn_kern(const short* __restrict__ qb,
                                                 const short* __restrict__ kb,
                                                 const short* __restrict__ vT,
                                                 short* __restrict__ yb) {
  __shared__ __align__(16) short Ks[2][64 * 128];   // 32 KB [row][chunk^(row&7)]
  __shared__ __align__(16) short Vs[128 * 64];      // 16 KB [d][chunk^(d&7)]
  __shared__ __align__(16) short Ps[128 * 64];      // 16 KB wave-private strips
  const int qt = 15 - (int)blockIdx.x;              // longest blocks dispatch first
  const int g  = blockIdx.y;
  const int b = g >> 4, h = g & 15, kvh = h >> 2;
  const int t = threadIdx.x, lane = t & 63, wave = t >> 6;   // wave 0..7
  const int lrow = lane & 15, quad = lane >> 4;
  const int q0 = qt * 128;
  const int KT = 2 * qt + 2;                        // k-tiles for 128 q-rows

  // staging geometry: per wave 2 insts each for K and V (16 insts total each)
  int k_row[2], k_col[2], v_row[2], v_col[2];
#pragma unroll
  for (int i = 0; i < 2; i++) {
    int wi = wave * 2 + i;                          // 0..15
    int kr = wi * 4 + (lane >> 4);                  // K rows 0..63
    k_row[i] = kr; k_col[i] = ((lane & 15) ^ (kr & 7)) * 8;
    int vr = wi * 8 + (lane >> 3);                  // V rows 0..127
    v_row[i] = vr; v_col[i] = ((lane & 7) ^ (vr & 7)) * 8;
  }
  const short* kbase = kb + (size_t)b * SEQ * KVD + kvh * HD;
  const short* vbase = vT + (size_t)(b * NKVH + kvh) * HD * SEQ;

  // all-ones B fragment for the l-sum MFMA
  bf16x8 vones;
#pragma unroll
  for (int j = 0; j < 8; j++) vones[j] = (__bf16)1.0f;

  // Q fragments in registers (1/sqrt(d), gain, log2e folded in)
  bf16x8 aq[4];
  const short* qrow = qb + (size_t)(b * SEQ + q0 + wave * 16 + lrow) * DIMN + h * HD;
#pragma unroll
  for (int kk = 0; kk < 4; kk++)
    aq[kk] = *(const bf16x8*)(qrow + kk * 32 + quad * 8);

  floatx4 O[8] = {};
  floatx4 Ol = {};                 // l accumulator, same row layout as O
  float mI[4];
#pragma unroll
  for (int r = 0; r < 4; r++) mI[r] = BIG_NEG;

  // prologue: stage K(0) into buf 0
#pragma unroll
  for (int i = 0; i < 2; i++)
    async_cp16(kbase + (size_t)k_row[i] * KVD + k_col[i], &Ks[0][(wave * 2 + i) * 512]);

  for (int kt = 0; kt < KT; kt++) {
    const int cur = kt & 1;
    const int k0 = kt * 64;
    __syncthreads();  // drains K(kt); all waves done with Vs(kt-1) reads

    // stage V(kt) + K(kt+1); drained at barrier-2 (hidden behind S+softmax)
#pragma unroll
    for (int i = 0; i < 2; i++)
      async_cp16(vbase + (size_t)v_row[i] * SEQ + k0 + v_col[i], &Vs[(wave * 2 + i) * 512]);
    if (kt + 1 < KT) {
      const int kn = k0 + 64;
#pragma unroll
      for (int i = 0; i < 2; i++)
        async_cp16(kbase + (size_t)(kn + k_row[i]) * KVD + k_col[i],
                   &Ks[cur ^ 1][(wave * 2 + i) * 512]);
    }

    // S = Q K^T (this wave: 16 rows of head h)
    floatx4 S[4] = {};
#pragma unroll
    for (int kk = 0; kk < 4; kk++)
#pragma unroll
      for (int nt = 0; nt < 4; nt++) {
        int row = nt * 16 + lrow;
        bf16x8 bk = *(const bf16x8*)&Ks[cur][row * 128 + ((kk * 4 + quad) ^ (row & 7)) * 8];
        S[nt] = __builtin_amdgcn_mfma_f32_16x16x32_bf16(aq[kk], bk, S[nt], 0, 0, 0);
      }

    if (kt >= 2 * qt) {  // last two tiles overlap the diagonal: global mask
#pragma unroll
      for (int nt = 0; nt < 4; nt++) {
        int kglob = k0 + nt * 16 + lrow;
#pragma unroll
        for (int r = 0; r < 4; r++) {
          int qglob = q0 + wave * 16 + quad * 4 + r;
          if (kglob > qglob) S[nt][r] = BIG_NEG;
        }
      }
    }
    // note: fully-masked rows (waves 0-3 at kt=2qt+1) are safe: mI was set by
    // earlier tiles, exp2(BIG_NEG - mI) flushes to 0.

    // online softmax (exp2 domain) with deferred-max rescale:
    // skip the alpha pass while the tile max grows by <= 8 (P bounded by 2^8)
#pragma unroll
    for (int r = 0; r < 4; r++) {
      float mx = fmaxf(fmaxf(S[0][r], S[1][r]), fmaxf(S[2][r], S[3][r]));
      mx = fmaxf(mx, __shfl_xor(mx, 1));
      mx = fmaxf(mx, __shfl_xor(mx, 2));
      mx = fmaxf(mx, __shfl_xor(mx, 4));
      mx = fmaxf(mx, __shfl_xor(mx, 8));
      if (!__all(mx <= mI[r] + 8.0f)) {
        float mNew = fmaxf(mI[r], mx);
        float alpha = exp2f(mI[r] - mNew);
        mI[r] = mNew;
#pragma unroll
        for (int n2 = 0; n2 < 8; n2++) O[n2][r] *= alpha;
        Ol[r] *= alpha;
      }
#pragma unroll
      for (int nt = 0; nt < 4; nt++) S[nt][r] = exp2f(S[nt][r] - mI[r]);
    }

    // P write: wave-private strip, swizzled chunks
#pragma unroll
    for (int nt = 0; nt < 4; nt++) {
      int cwr = ((nt * 2 + (lrow >> 3)) ^ (quad * 2)) * 8 + (lrow & 7);
#pragma unroll
      for (int r = 0; r < 4; r++)
        Ps[(wave * 16 + quad * 4 + r) * 64 + cwr] = bf16rn(S[nt][r]);
    }

    __syncthreads();  // drains V(kt) (+K(kt+1)); Vs ready

    // O += P V ; l-row-sum via MFMA with ones-B
#pragma unroll
    for (int kk = 0; kk < 2; kk++) {
      int capc = ((kk * 4 + quad) ^ (2 * ((lrow >> 2) & 3))) * 8;
      bf16x8 ap = *(const bf16x8*)&Ps[(wave * 16 + lrow) * 64 + capc];
#pragma unroll
      for (int n2 = 0; n2 < 8; n2++) {
        int row = n2 * 16 + lrow;
        bf16x8 bv = *(const bf16x8*)&Vs[row * 64 + ((kk * 4 + quad) ^ (row & 7)) * 8];
        O[n2] = __builtin_amdgcn_mfma_f32_16x16x32_bf16(ap, bv, O[n2], 0, 0, 0);
      }
      Ol = __builtin_amdgcn_mfma_f32_16x16x32_bf16(ap, vones, Ol, 0, 0, 0);
    }
  }

  // epilogue: this wave's 16 rows x 128 dims of head h
  float il[4];
#pragma unroll
  for (int r = 0; r < 4; r++) il[r] = 1.0f / Ol[r];
#pragma unroll
  for (int n2 = 0; n2 < 8; n2++)
#pragma unroll
    for (int r = 0; r < 4; r++) {
      float val = O[n2][r] * il[r];
      int row = q0 + wave * 16 + quad * 4 + r;
      int col = h * HD + n2 * 16 + lrow;
      yb[(size_t)(b * SEQ + row) * DIMN + col] = bf16rn(val);
    }
}

// ----------------------------------------------------------------- launch
extern "C" void kernel_launch(void* const* d_in, const int* in_sizes, int n_in,
                              void* d_out, int out_size, void* d_ws, size_t ws_size,
                              hipStream_t stream) {
  const float* x      = (const float*)d_in[0];
  const float* q_gain = (const float*)d_in[1];
  const float* W_q    = (const float*)d_in[2];
  const float* W_k    = (const float*)d_in[3];
  const float* W_v    = (const float*)d_in[4];
  const float* W_proj = (const float*)d_in[5];
  float* out = (float*)d_out;
  char* ws = (char*)d_ws;

  short* xb    = (short*)(ws);                // MROWS*DIMN bf16   16.78 MB
  short* wqkv  = (short*)(ws + 16777216);     // NQKV*DIMN bf16    12.58 MB
  short* wproj = (short*)(ws + 29360128);     // DIMN*DIMN bf16     8.39 MB
  short* qkvb  = (short*)(ws + 37748736);     // MROWS*NQKV bf16   25.17 MB
  short* q     = (short*)(ws + 62914560);     // MROWS*DIMN bf16   16.78 MB
  short* k     = (short*)(ws + 79691776);     // MROWS*KVD bf16     4.19 MB
  short* vT    = (short*)(ws + 83886080);     // transposed V bf16  4.19 MB
  short* y     = xb;                          // alias: xb dead after QKV GEMM
  float2* tab  = (float2*)xb;                 // alias: rope table lives in xb
                                              // after qkv GEMM, dead before attn
                                              // writes y (1 MB)

  auto cvt = [&](const float* src, short* dst, int n) {
    int n8 = n / 8;
    f32_to_bf16_kern<<<(n8 + 255) / 256, 256, 0, stream>>>(src, dst, n8);
  };
  cvt(x, xb, MROWS * DIMN);
  cvt(W_q, wqkv, DIMN * DIMN);
  cvt(W_k, wqkv + DIMN * DIMN, KVD * DIMN);
  cvt(W_v, wqkv + DIMN * DIMN + KVD * DIMN, KVD * DIMN);
  cvt(W_proj, wproj, DIMN * DIMN);

  // qkv (bf16) = x @ [Wq;Wk;Wv]^T
  gemm_bt_as<short><<<dim3(NQKV / 128, MROWS / 128), 256, 0, stream>>>(xb, wqkv, qkvb, NQKV, DIMN);
  // rope table into (now dead) xb region, then norm+rope
  rope_tab_kern<<<(SEQ * 64) / 256, 256, 0, stream>>>(tab);
  rms_rope_kern<<<(MROWS * 20) / 4, 256, 0, stream>>>(qkvb, q_gain, tab, q, k);
  vT_kern<<<dim3(SEQ / 64, HD / 64, BATCH * NKVH), 256, 0, stream>>>(qkvb, vT);
  attn_kern<<<dim3(16, 32), 512, 0, stream>>>(q, k, vT, y);
  // out (f32) = y @ Wproj^T
  gemm_bt_as<float><<<dim3(DIMN / 128, MROWS / 128), 256, 0, stream>>>(y, wproj, out, DIMN, DIMN);
}

// Round 6
// 323.413 us; speedup vs baseline: 1.2659x; 1.2659x over previous
//
#include <hip/hip_runtime.h>
#include <hip/hip_bf16.h>
#include <type_traits>

// Problem constants
#define DIMN   2048
#define NH     16
#define NKVH   4
#define HD     128
#define KVD    512        // NKVH*HD
#define NQKV   3072       // DIMN + 2*KVD
#define BATCH  2
#define SEQ    2048
#define MROWS  4096       // BATCH*SEQ
#define VOFF   2560       // DIMN + KVD: v offset inside qkv row

typedef __attribute__((ext_vector_type(8))) __bf16 bf16x8;
typedef __attribute__((ext_vector_type(4))) float floatx4;

#define BIG_NEG (-1.0e30f)

// hardware RTNE f32->bf16 (v_cvt_pk_bf16_f32)
__device__ __forceinline__ short bf16rn(float f) {
  union { __bf16 h; short s; } u;
  u.h = (__bf16)f;
  return u.s;
}
__device__ __forceinline__ float bf2f(short s) {
  union { unsigned u; float f; } v;
  v.u = ((unsigned)(unsigned short)s) << 16;
  return v.f;
}
__device__ __forceinline__ unsigned pack2bf(float a, float b) {
  return (unsigned)(unsigned short)bf16rn(a) |
         ((unsigned)(unsigned short)bf16rn(b) << 16);
}

// async 16B global -> LDS. LDS dest = wave-uniform base + lane*16 B;
// one instruction covers 64 lanes * 16 B = 512 shorts.
__device__ __forceinline__ void async_cp16(const short* g, short* l) {
  __builtin_amdgcn_global_load_lds(
      (const __attribute__((address_space(1))) unsigned int*)g,
      (__attribute__((address_space(3))) unsigned int*)l, 16, 0, 0);
}

// ---------------------------------------------------------------- f32 -> bf16
__global__ void f32_to_bf16_kern(const float* __restrict__ in,
                                 short* __restrict__ out, int n8) {
  int i = blockIdx.x * blockDim.x + threadIdx.x;
  if (i >= n8) return;
  float4 a = ((const float4*)in)[i * 2];
  float4 b = ((const float4*)in)[i * 2 + 1];
  short r[8];
  r[0] = bf16rn(a.x); r[1] = bf16rn(a.y); r[2] = bf16rn(a.z); r[3] = bf16rn(a.w);
  r[4] = bf16rn(b.x); r[5] = bf16rn(b.y); r[6] = bf16rn(b.z); r[7] = bf16rn(b.w);
  ((uint4*)out)[i] = *(const uint4*)r;
}

// --------------------------------------------------- C[M][N] = A[M][K] B[N][K]^T
// 128x128 tile, BK=32, double-buffered global_load_lds staging, one barrier per
// K-iter. XOR-swizzled LDS (stored chunk = logical ^ (row&3)). OUT: float or
// bf16 (short) epilogue.
template <typename OUT>
__global__ __launch_bounds__(256) void gemm_bt_as(const short* __restrict__ A,
                                                  const short* __restrict__ Bw,
                                                  OUT* __restrict__ C,
                                                  int N, int K) {
  __shared__ __align__(16) short As[2][128 * 32];
  __shared__ __align__(16) short Bs[2][128 * 32];
  const int t = threadIdx.x;
  const int lane = t & 63, wave = t >> 6;
  const int lrow = lane & 15, quad = lane >> 4;
  const int wr = wave >> 1, wc = wave & 1;
  const int m0 = blockIdx.y * 128, n0 = blockIdx.x * 128;

  const short* pa[2];
  const short* pb[2];
  int wi2[2];
#pragma unroll
  for (int i = 0; i < 2; i++) {
    int wi = wave * 2 + i;
    int row = wi * 16 + (lane >> 2);
    int col = ((lane & 3) ^ (row & 3)) * 8;
    pa[i] = A + (size_t)(m0 + row) * K + col;
    pb[i] = Bw + (size_t)(n0 + row) * K + col;
    wi2[i] = wi;
  }

  floatx4 acc[4][4] = {};
  const int iters = K >> 5;

#pragma unroll
  for (int i = 0; i < 2; i++) {
    async_cp16(pa[i], &As[0][wi2[i] * 512]);
    async_cp16(pb[i], &Bs[0][wi2[i] * 512]);
  }

  for (int it = 0; it < iters; it++) {
    const int cur = it & 1;
    __syncthreads();   // drains stage(it); prior iter's reads of buf[cur^1] done

    if (it + 1 < iters) {
      const int off = (it + 1) * 32;
#pragma unroll
      for (int i = 0; i < 2; i++) {
        async_cp16(pa[i] + off, &As[cur ^ 1][wi2[i] * 512]);
        async_cp16(pb[i] + off, &Bs[cur ^ 1][wi2[i] * 512]);
      }
    }

    bf16x8 af[4], bfr[4];
#pragma unroll
    for (int mt = 0; mt < 4; mt++) {
      int row = wr * 64 + mt * 16 + lrow;
      af[mt] = *(const bf16x8*)&As[cur][row * 32 + (quad ^ (lrow & 3)) * 8];
    }
#pragma unroll
    for (int nt = 0; nt < 4; nt++) {
      int row = wc * 64 + nt * 16 + lrow;
      bfr[nt] = *(const bf16x8*)&Bs[cur][row * 32 + (quad ^ (lrow & 3)) * 8];
    }
#pragma unroll
    for (int mt = 0; mt < 4; mt++)
#pragma unroll
      for (int nt = 0; nt < 4; nt++)
        acc[mt][nt] = __builtin_amdgcn_mfma_f32_16x16x32_bf16(af[mt], bfr[nt],
                                                              acc[mt][nt], 0, 0, 0);
  }

#pragma unroll
  for (int mt = 0; mt < 4; mt++)
#pragma unroll
    for (int nt = 0; nt < 4; nt++) {
      int row = m0 + wr * 64 + mt * 16 + quad * 4;
      int col = n0 + wc * 64 + nt * 16 + lrow;
#pragma unroll
      for (int r = 0; r < 4; r++) {
        if constexpr (std::is_same<OUT, short>::value)
          C[(size_t)(row + r) * N + col] = bf16rn(acc[mt][nt][r]);
        else
          C[(size_t)(row + r) * N + col] = acc[mt][nt][r];
      }
    }
}

// ---------------------------------------------------- rope cos/sin table (once)
// tab[pos*64 + ln] = (cos, sin) of pos * 10000^(-ln/64). Bit-identical math to
// per-element computation, done SEQ*64 times instead of 40x that. (Proven R5.)
__global__ void rope_tab_kern(float2* __restrict__ tab) {
  int i = blockIdx.x * 256 + threadIdx.x;
  int pos = i >> 6, ln = i & 63;
  float fr = (float)pos * exp2f((float)ln * -0.20762050593045935f);
  float s, c;
  sincosf(fr, &s, &c);
  tab[i] = make_float2(c, s);
}

// -------------------------------------------- per-(row,head): RMSNorm+RoPE+gain
// qkv bf16. one wave per (row, slot): slots 0..15 = q heads, 16..19 = k heads
__global__ __launch_bounds__(256) void rms_rope_kern(const short* __restrict__ qkv,
                                                     const float* __restrict__ gain,
                                                     const float2* __restrict__ tab,
                                                     short* __restrict__ qb,
                                                     short* __restrict__ kb) {
  const int t = threadIdx.x;
  const int lane = t & 63, wave = t >> 6;
  const int gw = blockIdx.x * 4 + wave;
  const int row = gw / 20, slot = gw - row * 20;
  const int pos = row & (SEQ - 1);

  const short* src = (slot < 16) ? qkv + (size_t)row * NQKV + slot * HD
                                 : qkv + (size_t)row * NQKV + DIMN + (slot - 16) * HD;
  float x1 = bf2f(src[lane]), x2 = bf2f(src[lane + 64]);

  float ss = x1 * x1 + x2 * x2;
#pragma unroll
  for (int off = 32; off > 0; off >>= 1) ss += __shfl_xor(ss, off);
  float inv = rsqrtf(ss * (1.0f / 128.0f) + 1.1920928955078125e-7f);
  x1 *= inv; x2 *= inv;
  float2 cs = tab[pos * 64 + lane];
  float c = cs.x, s = cs.y;
  float y1 = x1 * c + x2 * s;
  float y2 = x2 * c - x1 * s;
  if (slot < 16) {
    // q_gain * 1/sqrt(HD) * log2(e): softmax then uses exp2 directly
    float g = gain[slot] * 0.12751744459132754f;
    y1 *= g; y2 *= g;
  }
  short o1 = bf16rn(y1), o2 = bf16rn(y2);
  if (slot < 16) { short* d = qb + (size_t)row * DIMN + slot * HD;        d[lane] = o1; d[lane + 64] = o2; }
  else           { short* d = kb + (size_t)row * KVD + (slot - 16) * HD;  d[lane] = o1; d[lane + 64] = o2; }
}

// ------------------------------------- v transpose: qkv bf16 [t][d] -> vT bf16 [d][t]
__global__ __launch_bounds__(256) void vT_kern(const short* __restrict__ qkv,
                                               short* __restrict__ vT) {
  __shared__ short L[64 * 68];
  const int t0 = blockIdx.x * 64, d0 = blockIdx.y * 64;
  const int b = blockIdx.z >> 2, kvh = blockIdx.z & 3;
  const int t = threadIdx.x;

#pragma unroll
  for (int p = 0; p < 4; p++) {
    int tt = p * 16 + (t >> 4);
    int dd = (t & 15) * 4;
    ushort4 v = *(const ushort4*)(qkv + (size_t)(b * SEQ + t0 + tt) * NQKV + VOFF + kvh * HD + d0 + dd);
    *(ushort4*)&L[tt * 68 + dd] = v;
  }
  __syncthreads();

  const int dl = t >> 2;
  const int tc = (t & 3) * 16;
  short tmp[16];
#pragma unroll
  for (int j = 0; j < 16; j++) tmp[j] = L[(tc + j) * 68 + dl];
  size_t obase = (size_t)((b * NKVH + kvh) * HD + d0 + dl) * SEQ + t0 + tc;
  *(uint4*)(vT + obase)     = ((const uint4*)tmp)[0];
  *(uint4*)(vT + obase + 8) = ((const uint4*)tmp)[1];
}

// ------------------------------------------------------- causal flash attention
// ROUND 6: SWAPPED-OPERAND MFMA, lane-local softmax. Skeleton = proven R1
// (grid (16 qp, 32 bh), 4 waves, qp-paired uniform 33 tiles, Ks double-buffered,
// V staged at tile top + drained at barrier-2, 2 barriers/tile). Both GEMMs
// computed transposed: S^T = mfma(K_frag, Q_frag), O^T = mfma(V_frag, P_frag).
// A- and B-fragment layouts read IDENTICAL bytes from our LDS tiles, so K/V
// staging and swizzles are untouched; only the C layout flips:
//   S^T: q = lane&15, k = nt*16 + quad*4 + r  -> softmax is per-LANE:
//   15 in-lane fmax + 2 shfl_xor (vs 16 chained shfls), scalar alpha/mI/l.
// P repack (S^T-layout -> PV B-operand) via 8 KB wave-private LDS strip,
// 8x b32 write + 8x b32 read, XOR-swizzle W = q*32 + (kw ^ (q&15) ^ (kw>>3&1)<<4)
// (bijective; reads 2-way = free, writes 4-way on 8 instrs = negligible).
// O^T: q = lane&15, d = n2*16 + quad*4 + r -> per-lane 1/l scale, uint2 stores.
__global__ __launch_bounds__(256) void attn_kern(const short* __restrict__ qb,
                                                 const short* __restrict__ kb,
                                                 const short* __restrict__ vT,
                                                 short* __restrict__ yb) {
  __shared__ __align__(16) short Ks[2][64 * 128];   // 32 KB [row][chunk^(row&7)]
  __shared__ __align__(16) short Vs[128 * 64];      // 16 KB [d][chunk^(d&7)]
  __shared__ __align__(16) unsigned Psw[64 * 32];   //  8 KB wave-private P strips
  const int qp = blockIdx.x;
  const int g  = blockIdx.y;
  const int b = g >> 4, h = g & 15, kvh = h >> 2;
  const int t = threadIdx.x, lane = t & 63, wave = t >> 6;
  const int lrow = lane & 15, quad = lane >> 4;
  const int qrow = wave * 16 + lrow;                // this lane's q-row (0..63)

  // staging geometry: per wave inst wi = wave*4 + i (0..15)
  int k_row[4], k_col[4], v_row[4], v_col[4];
#pragma unroll
  for (int i = 0; i < 4; i++) {
    int wi = wave * 4 + i;
    int kr = wi * 4 + (lane >> 4);
    k_row[i] = kr; k_col[i] = ((lane & 15) ^ (kr & 7)) * 8;
    int vr = wi * 8 + (lane >> 3);
    v_row[i] = vr; v_col[i] = ((lane & 7) ^ (vr & 7)) * 8;
  }
  const short* kbase = kb + (size_t)b * SEQ * KVD + kvh * HD;
  const short* vbase = vT + (size_t)(b * NKVH + kvh) * HD * SEQ;

  // all-ones A fragment for the l-sum MFMA (C[m][q] = sum_k P[q][k], all m equal)
  bf16x8 vones;
#pragma unroll
  for (int j = 0; j < 8; j++) vones[j] = (__bf16)1.0f;

  for (int ph = 0; ph < 2; ph++) {
    const int qt = ph ? (31 - qp) : qp;
    const int q0 = qt * 64;

    __syncthreads();  // all waves done with previous phase's LDS reads

    // Q fragments in registers (1/sqrt(d), gain, log2e folded in).
    // Serves as the swapped-mfma B operand: lane holds Q[q=lane&15][d-chunk by quad].
    bf16x8 aq[4];
    const short* qrw = qb + (size_t)(b * SEQ + q0 + qrow) * DIMN + h * HD;
#pragma unroll
    for (int kk = 0; kk < 4; kk++)
      aq[kk] = *(const bf16x8*)(qrw + kk * 32 + quad * 8);

    floatx4 O[8] = {};         // O^T: d = n2*16 + quad*4 + r, q = lane&15
    floatx4 Ol = {};           // l accumulator (all 4 rows identical)
    float mI = BIG_NEG;        // per-lane running max for q = lane&15

    // prologue: stage K(0) into buf 0
#pragma unroll
    for (int i = 0; i < 4; i++)
      async_cp16(kbase + (size_t)k_row[i] * KVD + k_col[i], &Ks[0][(wave * 4 + i) * 512]);

    for (int kt = 0; kt <= qt; kt++) {
      const int cur = kt & 1;
      const int k0 = kt * 64;
      __syncthreads();  // drains K(kt); all waves done with Vs(kt-1) reads

      // stage V(kt) + K(kt+1); drained at barrier-2 (hidden behind S+softmax)
#pragma unroll
      for (int i = 0; i < 4; i++)
        async_cp16(vbase + (size_t)v_row[i] * SEQ + k0 + v_col[i], &Vs[(wave * 4 + i) * 512]);
      if (kt < qt) {
        const int kn = k0 + 64;
#pragma unroll
        for (int i = 0; i < 4; i++)
          async_cp16(kbase + (size_t)(kn + k_row[i]) * KVD + k_col[i],
                     &Ks[cur ^ 1][(wave * 4 + i) * 512]);
      }

      // S^T = (Q K^T)^T via swapped operands: St[nt] has k = nt*16+quad*4+r,
      // q = lane&15. K-frag (A) and Q-frag (B) read the same bytes as before.
      floatx4 St[4] = {};
#pragma unroll
      for (int kk = 0; kk < 4; kk++)
#pragma unroll
        for (int nt = 0; nt < 4; nt++) {
          int row = nt * 16 + lrow;
          bf16x8 bk = *(const bf16x8*)&Ks[cur][row * 128 + ((kk * 4 + quad) ^ (row & 7)) * 8];
          St[nt] = __builtin_amdgcn_mfma_f32_16x16x32_bf16(bk, aq[kk], St[nt], 0, 0, 0);
        }

      if (kt == qt) {  // diagonal: causal mask (in-tile indices, tiles aligned)
#pragma unroll
        for (int nt = 0; nt < 4; nt++)
#pragma unroll
          for (int r = 0; r < 4; r++) {
            int kj = nt * 16 + quad * 4 + r;
            if (kj > qrow) St[nt][r] = BIG_NEG;
          }
      }

      // lane-local online softmax (exp2 domain), defer-max rescale (THR=8)
      float mx = St[0][0];
#pragma unroll
      for (int nt = 0; nt < 4; nt++)
#pragma unroll
        for (int r = 0; r < 4; r++) mx = fmaxf(mx, St[nt][r]);
      mx = fmaxf(mx, __shfl_xor(mx, 16));
      mx = fmaxf(mx, __shfl_xor(mx, 32));
      if (!__all(mx <= mI + 8.0f)) {
        float mNew = fmaxf(mI, mx);
        float alpha = exp2f(mI - mNew);
        mI = mNew;
#pragma unroll
        for (int n2 = 0; n2 < 8; n2++) O[n2] *= alpha;
        Ol *= alpha;
      }
#pragma unroll
      for (int nt = 0; nt < 4; nt++)
#pragma unroll
        for (int r = 0; r < 4; r++) St[nt][r] = exp2f(St[nt][r] - mI);

      // P repack: write lane's 16 values (k = nt*16+quad*4+r) as 8 packed u32
      // into the wave-private strip; swizzle is a bijection of (q, kw).
#pragma unroll
      for (int nt = 0; nt < 4; nt++)
#pragma unroll
        for (int hh = 0; hh < 2; hh++) {
          int kw = nt * 8 + quad * 2 + hh;
          Psw[qrow * 32 + (kw ^ lrow ^ (((kw >> 3) & 1) << 4))] =
              pack2bf(St[nt][2 * hh], St[nt][2 * hh + 1]);
        }

      __syncthreads();  // drains V(kt) (+K(kt+1)); Vs ready

      // O^T += (P V)^T via swapped operands: V-frag (A) reads same bytes as
      // before; P-frag (B) = lane holds P[q=lane&15][k = kk*32+quad*8+j].
#pragma unroll
      for (int kk = 0; kk < 2; kk++) {
        union { unsigned u[4]; bf16x8 v; } bp;
#pragma unroll
        for (int j2 = 0; j2 < 4; j2++) {
          int kw = kk * 16 + quad * 4 + j2;
          bp.u[j2] = Psw[qrow * 32 + (kw ^ lrow ^ (((kw >> 3) & 1) << 4))];
        }
#pragma unroll
        for (int n2 = 0; n2 < 8; n2++) {
          int row = n2 * 16 + lrow;
          bf16x8 bv = *(const bf16x8*)&Vs[row * 64 + ((kk * 4 + quad) ^ (row & 7)) * 8];
          O[n2] = __builtin_amdgcn_mfma_f32_16x16x32_bf16(bv, bp.v, O[n2], 0, 0, 0);
        }
        Ol = __builtin_amdgcn_mfma_f32_16x16x32_bf16(vones, bp.v, Ol, 0, 0, 0);
      }
    }

    // epilogue: lane owns q = q0 + qrow; d = n2*16 + quad*4 + r
    float il = 1.0f / Ol[0];
    short* yrow = yb + (size_t)(b * SEQ + q0 + qrow) * DIMN + h * HD;
#pragma unroll
    for (int n2 = 0; n2 < 8; n2++) {
      short o[4];
#pragma unroll
      for (int r = 0; r < 4; r++) o[r] = bf16rn(O[n2][r] * il);
      *(uint2*)&yrow[n2 * 16 + quad * 4] = *(const uint2*)o;
    }
  }
}

// ----------------------------------------------------------------- launch
extern "C" void kernel_launch(void* const* d_in, const int* in_sizes, int n_in,
                              void* d_out, int out_size, void* d_ws, size_t ws_size,
                              hipStream_t stream) {
  const float* x      = (const float*)d_in[0];
  const float* q_gain = (const float*)d_in[1];
  const float* W_q    = (const float*)d_in[2];
  const float* W_k    = (const float*)d_in[3];
  const float* W_v    = (const float*)d_in[4];
  const float* W_proj = (const float*)d_in[5];
  float* out = (float*)d_out;
  char* ws = (char*)d_ws;

  short* xb    = (short*)(ws);                // MROWS*DIMN bf16   16.78 MB
  short* wqkv  = (short*)(ws + 16777216);     // NQKV*DIMN bf16    12.58 MB
  short* wproj = (short*)(ws + 29360128);     // DIMN*DIMN bf16     8.39 MB
  short* qkvb  = (short*)(ws + 37748736);     // MROWS*NQKV bf16   25.17 MB
  short* q     = (short*)(ws + 62914560);     // MROWS*DIMN bf16   16.78 MB
  short* k     = (short*)(ws + 79691776);     // MROWS*KVD bf16     4.19 MB
  short* vT    = (short*)(ws + 83886080);     // transposed V bf16  4.19 MB
  short* y     = xb;                          // alias: xb dead after QKV GEMM
  float2* tab  = (float2*)xb;                 // alias: rope table in dead xb

  auto cvt = [&](const float* src, short* dst, int n) {
    int n8 = n / 8;
    f32_to_bf16_kern<<<(n8 + 255) / 256, 256, 0, stream>>>(src, dst, n8);
  };
  cvt(x, xb, MROWS * DIMN);
  cvt(W_q, wqkv, DIMN * DIMN);
  cvt(W_k, wqkv + DIMN * DIMN, KVD * DIMN);
  cvt(W_v, wqkv + DIMN * DIMN + KVD * DIMN, KVD * DIMN);
  cvt(W_proj, wproj, DIMN * DIMN);

  // qkv (bf16) = x @ [Wq;Wk;Wv]^T
  gemm_bt_as<short><<<dim3(NQKV / 128, MROWS / 128), 256, 0, stream>>>(xb, wqkv, qkvb, NQKV, DIMN);
  // rope table into (now dead) xb region, then norm+rope
  rope_tab_kern<<<(SEQ * 64) / 256, 256, 0, stream>>>(tab);
  rms_rope_kern<<<(MROWS * 20) / 4, 256, 0, stream>>>(qkvb, q_gain, tab, q, k);
  vT_kern<<<dim3(SEQ / 64, HD / 64, BATCH * NKVH), 256, 0, stream>>>(qkvb, vT);
  attn_kern<<<dim3(16, 32), 256, 0, stream>>>(q, k, vT, y);
  // out (f32) = y @ Wproj^T
  gemm_bt_as<float><<<dim3(DIMN / 128, MROWS / 128), 256, 0, stream>>>(y, wproj, out, DIMN, DIMN);
}

// Round 7
// 322.543 us; speedup vs baseline: 1.2693x; 1.0027x over previous
//
#include <hip/hip_runtime.h>
#include <hip/hip_bf16.h>
#include <type_traits>

// Problem constants
#define DIMN   2048
#define NH     16
#define NKVH   4
#define HD     128
#define KVD    512        // NKVH*HD
#define NQKV   3072       // DIMN + 2*KVD
#define BATCH  2
#define SEQ    2048
#define MROWS  4096       // BATCH*SEQ
#define VOFF   2560       // DIMN + KVD: v offset inside qkv row

typedef __attribute__((ext_vector_type(8))) __bf16 bf16x8;
typedef __attribute__((ext_vector_type(4))) float floatx4;

#define BIG_NEG (-1.0e30f)

// hardware RTNE f32->bf16 (v_cvt_pk_bf16_f32)
__device__ __forceinline__ short bf16rn(float f) {
  union { __bf16 h; short s; } u;
  u.h = (__bf16)f;
  return u.s;
}
__device__ __forceinline__ float bf2f(short s) {
  union { unsigned u; float f; } v;
  v.u = ((unsigned)(unsigned short)s) << 16;
  return v.f;
}
__device__ __forceinline__ unsigned pack2bf(float a, float b) {
  return (unsigned)(unsigned short)bf16rn(a) |
         ((unsigned)(unsigned short)bf16rn(b) << 16);
}

// async 16B global -> LDS. LDS dest = wave-uniform base + lane*16 B;
// one instruction covers 64 lanes * 16 B = 512 shorts.
__device__ __forceinline__ void async_cp16(const short* g, short* l) {
  __builtin_amdgcn_global_load_lds(
      (const __attribute__((address_space(1))) unsigned int*)g,
      (__attribute__((address_space(3))) unsigned int*)l, 16, 0, 0);
}

// ---------------------------------------------------------------- f32 -> bf16
__global__ void f32_to_bf16_kern(const float* __restrict__ in,
                                 short* __restrict__ out, int n8) {
  int i = blockIdx.x * blockDim.x + threadIdx.x;
  if (i >= n8) return;
  float4 a = ((const float4*)in)[i * 2];
  float4 b = ((const float4*)in)[i * 2 + 1];
  short r[8];
  r[0] = bf16rn(a.x); r[1] = bf16rn(a.y); r[2] = bf16rn(a.z); r[3] = bf16rn(a.w);
  r[4] = bf16rn(b.x); r[5] = bf16rn(b.y); r[6] = bf16rn(b.z); r[7] = bf16rn(b.w);
  ((uint4*)out)[i] = *(const uint4*)r;
}

// --------------------------------------------------- C[M][N] = A[M][K] B[N][K]^T
// 128x128 tile, BK=32, double-buffered global_load_lds staging, one barrier per
// K-iter. XOR-swizzled LDS (stored chunk = logical ^ (row&3)). OUT: float or
// bf16 (short) epilogue. R7: T1 chunked XCD swizzle (grid %8==0 -> bijective):
// XCD j gets a CONTIGUOUS chunk of logical tile space -> neighboring tiles
// sharing A/B panels hit the same per-XCD L2.
template <typename OUT>
__global__ __launch_bounds__(256) void gemm_bt_as(const short* __restrict__ A,
                                                  const short* __restrict__ Bw,
                                                  OUT* __restrict__ C,
                                                  int N, int K) {
  __shared__ __align__(16) short As[2][128 * 32];
  __shared__ __align__(16) short Bs[2][128 * 32];
  const int t = threadIdx.x;
  const int lane = t & 63, wave = t >> 6;
  const int lrow = lane & 15, quad = lane >> 4;
  const int wr = wave >> 1, wc = wave & 1;

  const int nbx = gridDim.x;
  const int nwg = nbx * gridDim.y;          // 768 or 512: both % 8 == 0
  const int id  = blockIdx.y * nbx + blockIdx.x;
  const int nid = (id & 7) * (nwg >> 3) + (id >> 3);   // m157 bijective form
  const int m0 = (nid / nbx) * 128, n0 = (nid % nbx) * 128;

  const short* pa[2];
  const short* pb[2];
  int wi2[2];
#pragma unroll
  for (int i = 0; i < 2; i++) {
    int wi = wave * 2 + i;
    int row = wi * 16 + (lane >> 2);
    int col = ((lane & 3) ^ (row & 3)) * 8;
    pa[i] = A + (size_t)(m0 + row) * K + col;
    pb[i] = Bw + (size_t)(n0 + row) * K + col;
    wi2[i] = wi;
  }

  floatx4 acc[4][4] = {};
  const int iters = K >> 5;

#pragma unroll
  for (int i = 0; i < 2; i++) {
    async_cp16(pa[i], &As[0][wi2[i] * 512]);
    async_cp16(pb[i], &Bs[0][wi2[i] * 512]);
  }

  for (int it = 0; it < iters; it++) {
    const int cur = it & 1;
    __syncthreads();   // drains stage(it); prior iter's reads of buf[cur^1] done

    if (it + 1 < iters) {
      const int off = (it + 1) * 32;
#pragma unroll
      for (int i = 0; i < 2; i++) {
        async_cp16(pa[i] + off, &As[cur ^ 1][wi2[i] * 512]);
        async_cp16(pb[i] + off, &Bs[cur ^ 1][wi2[i] * 512]);
      }
    }

    bf16x8 af[4], bfr[4];
#pragma unroll
    for (int mt = 0; mt < 4; mt++) {
      int row = wr * 64 + mt * 16 + lrow;
      af[mt] = *(const bf16x8*)&As[cur][row * 32 + (quad ^ (lrow & 3)) * 8];
    }
#pragma unroll
    for (int nt = 0; nt < 4; nt++) {
      int row = wc * 64 + nt * 16 + lrow;
      bfr[nt] = *(const bf16x8*)&Bs[cur][row * 32 + (quad ^ (lrow & 3)) * 8];
    }
#pragma unroll
    for (int mt = 0; mt < 4; mt++)
#pragma unroll
      for (int nt = 0; nt < 4; nt++)
        acc[mt][nt] = __builtin_amdgcn_mfma_f32_16x16x32_bf16(af[mt], bfr[nt],
                                                              acc[mt][nt], 0, 0, 0);
  }

#pragma unroll
  for (int mt = 0; mt < 4; mt++)
#pragma unroll
    for (int nt = 0; nt < 4; nt++) {
      int row = m0 + wr * 64 + mt * 16 + quad * 4;
      int col = n0 + wc * 64 + nt * 16 + lrow;
#pragma unroll
      for (int r = 0; r < 4; r++) {
        if constexpr (std::is_same<OUT, short>::value)
          C[(size_t)(row + r) * N + col] = bf16rn(acc[mt][nt][r]);
        else
          C[(size_t)(row + r) * N + col] = acc[mt][nt][r];
      }
    }
}

// ---------------------------------------------------- rope cos/sin table (once)
// tab[pos*64 + ln] = (cos, sin) of pos * 10000^(-ln/64). Bit-identical math to
// per-element computation, done SEQ*64 times instead of 40x that. (Proven R5.)
__global__ void rope_tab_kern(float2* __restrict__ tab) {
  int i = blockIdx.x * 256 + threadIdx.x;
  int pos = i >> 6, ln = i & 63;
  float fr = (float)pos * exp2f((float)ln * -0.20762050593045935f);
  float s, c;
  sincosf(fr, &s, &c);
  tab[i] = make_float2(c, s);
}

// -------------------------------------------- per-(row,head): RMSNorm+RoPE+gain
// qkv bf16. one wave per (row, slot): slots 0..15 = q heads, 16..19 = k heads
__global__ __launch_bounds__(256) void rms_rope_kern(const short* __restrict__ qkv,
                                                     const float* __restrict__ gain,
                                                     const float2* __restrict__ tab,
                                                     short* __restrict__ qb,
                                                     short* __restrict__ kb) {
  const int t = threadIdx.x;
  const int lane = t & 63, wave = t >> 6;
  const int gw = blockIdx.x * 4 + wave;
  const int row = gw / 20, slot = gw - row * 20;
  const int pos = row & (SEQ - 1);

  const short* src = (slot < 16) ? qkv + (size_t)row * NQKV + slot * HD
                                 : qkv + (size_t)row * NQKV + DIMN + (slot - 16) * HD;
  float x1 = bf2f(src[lane]), x2 = bf2f(src[lane + 64]);

  float ss = x1 * x1 + x2 * x2;
#pragma unroll
  for (int off = 32; off > 0; off >>= 1) ss += __shfl_xor(ss, off);
  float inv = rsqrtf(ss * (1.0f / 128.0f) + 1.1920928955078125e-7f);
  x1 *= inv; x2 *= inv;
  float2 cs = tab[pos * 64 + lane];
  float c = cs.x, s = cs.y;
  float y1 = x1 * c + x2 * s;
  float y2 = x2 * c - x1 * s;
  if (slot < 16) {
    // q_gain * 1/sqrt(HD) * log2(e): softmax then uses exp2 directly
    float g = gain[slot] * 0.12751744459132754f;
    y1 *= g; y2 *= g;
  }
  short o1 = bf16rn(y1), o2 = bf16rn(y2);
  if (slot < 16) { short* d = qb + (size_t)row * DIMN + slot * HD;        d[lane] = o1; d[lane + 64] = o2; }
  else           { short* d = kb + (size_t)row * KVD + (slot - 16) * HD;  d[lane] = o1; d[lane + 64] = o2; }
}

// ------------------------------------- v transpose: qkv bf16 [t][d] -> vT bf16 [d][t]
__global__ __launch_bounds__(256) void vT_kern(const short* __restrict__ qkv,
                                               short* __restrict__ vT) {
  __shared__ short L[64 * 68];
  const int t0 = blockIdx.x * 64, d0 = blockIdx.y * 64;
  const int b = blockIdx.z >> 2, kvh = blockIdx.z & 3;
  const int t = threadIdx.x;

#pragma unroll
  for (int p = 0; p < 4; p++) {
    int tt = p * 16 + (t >> 4);
    int dd = (t & 15) * 4;
    ushort4 v = *(const ushort4*)(qkv + (size_t)(b * SEQ + t0 + tt) * NQKV + VOFF + kvh * HD + d0 + dd);
    *(ushort4*)&L[tt * 68 + dd] = v;
  }
  __syncthreads();

  const int dl = t >> 2;
  const int tc = (t & 3) * 16;
  short tmp[16];
#pragma unroll
  for (int j = 0; j < 16; j++) tmp[j] = L[(tc + j) * 68 + dl];
  size_t obase = (size_t)((b * NKVH + kvh) * HD + d0 + dl) * SEQ + t0 + tc;
  *(uint4*)(vT + obase)     = ((const uint4*)tmp)[0];
  *(uint4*)(vT + obase + 8) = ((const uint4*)tmp)[1];
}

// ------------------------------------------------------- causal flash attention
// R6 skeleton (swapped-operand MFMA, lane-local softmax) + R7 refinements:
//  (1) Psw swizzle bit4 = (kw>>2)&1 (quad-dependent on BOTH write and read
//      index patterns) -> writes 4-way->2-way conflict, reads stay 2-way.
//  (2) T5 s_setprio(1) around the two MFMA clusters (independent blocks per CU
//      at different phases -> scheduler has something to arbitrate; m191 +4-7%).
//  (3) XCD-aware block remap: group = id&7 = (b,kvh) -> all 64 blocks sharing
//      the same 1MB K/V slice land on one XCD's L2 (round-robin dispatch).
__global__ __launch_bounds__(256) void attn_kern(const short* __restrict__ qb,
                                                 const short* __restrict__ kb,
                                                 const short* __restrict__ vT,
                                                 short* __restrict__ yb) {
  __shared__ __align__(16) short Ks[2][64 * 128];   // 32 KB [row][chunk^(row&7)]
  __shared__ __align__(16) short Vs[128 * 64];      // 16 KB [d][chunk^(d&7)]
  __shared__ __align__(16) unsigned Psw[64 * 32];   //  8 KB wave-private P strips
  // XCD-aware remap: raw id 0..511 -> (G=b*4+kvh, hh, qp); G = id&7 pins each
  // (b,kvh) group (shared K/V) to one XCD under round-robin dispatch.
  const int rawid = (int)blockIdx.y * 16 + (int)blockIdx.x;
  const int G = rawid & 7;
  const int rest = rawid >> 3;                      // 0..63
  const int b = G >> 2, kvh = G & 3;
  const int h = kvh * 4 + (rest & 3);
  const int qp = rest >> 2;                         // 0..15
  const int t = threadIdx.x, lane = t & 63, wave = t >> 6;
  const int lrow = lane & 15, quad = lane >> 4;
  const int qrow = wave * 16 + lrow;                // this lane's q-row (0..63)

  // staging geometry: per wave inst wi = wave*4 + i (0..15)
  int k_row[4], k_col[4], v_row[4], v_col[4];
#pragma unroll
  for (int i = 0; i < 4; i++) {
    int wi = wave * 4 + i;
    int kr = wi * 4 + (lane >> 4);
    k_row[i] = kr; k_col[i] = ((lane & 15) ^ (kr & 7)) * 8;
    int vr = wi * 8 + (lane >> 3);
    v_row[i] = vr; v_col[i] = ((lane & 7) ^ (vr & 7)) * 8;
  }
  const short* kbase = kb + (size_t)b * SEQ * KVD + kvh * HD;
  const short* vbase = vT + (size_t)(b * NKVH + kvh) * HD * SEQ;

  // all-ones A fragment for the l-sum MFMA (C[m][q] = sum_k P[q][k], all m equal)
  bf16x8 vones;
#pragma unroll
  for (int j = 0; j < 8; j++) vones[j] = (__bf16)1.0f;

  for (int ph = 0; ph < 2; ph++) {
    const int qt = ph ? (31 - qp) : qp;
    const int q0 = qt * 64;

    __syncthreads();  // all waves done with previous phase's LDS reads

    // Q fragments in registers (1/sqrt(d), gain, log2e folded in).
    // Serves as the swapped-mfma B operand: lane holds Q[q=lane&15][d-chunk by quad].
    bf16x8 aq[4];
    const short* qrw = qb + (size_t)(b * SEQ + q0 + qrow) * DIMN + h * HD;
#pragma unroll
    for (int kk = 0; kk < 4; kk++)
      aq[kk] = *(const bf16x8*)(qrw + kk * 32 + quad * 8);

    floatx4 O[8] = {};         // O^T: d = n2*16 + quad*4 + r, q = lane&15
    floatx4 Ol = {};           // l accumulator (all 4 rows identical)
    float mI = BIG_NEG;        // per-lane running max for q = lane&15

    // prologue: stage K(0) into buf 0
#pragma unroll
    for (int i = 0; i < 4; i++)
      async_cp16(kbase + (size_t)k_row[i] * KVD + k_col[i], &Ks[0][(wave * 4 + i) * 512]);

    for (int kt = 0; kt <= qt; kt++) {
      const int cur = kt & 1;
      const int k0 = kt * 64;
      __syncthreads();  // drains K(kt); all waves done with Vs(kt-1) reads

      // stage V(kt) + K(kt+1); drained at barrier-2 (hidden behind S+softmax)
#pragma unroll
      for (int i = 0; i < 4; i++)
        async_cp16(vbase + (size_t)v_row[i] * SEQ + k0 + v_col[i], &Vs[(wave * 4 + i) * 512]);
      if (kt < qt) {
        const int kn = k0 + 64;
#pragma unroll
        for (int i = 0; i < 4; i++)
          async_cp16(kbase + (size_t)(kn + k_row[i]) * KVD + k_col[i],
                     &Ks[cur ^ 1][(wave * 4 + i) * 512]);
      }

      // S^T = (Q K^T)^T via swapped operands: St[nt] has k = nt*16+quad*4+r,
      // q = lane&15. K-frag (A) and Q-frag (B) read the same bytes as before.
      floatx4 St[4] = {};
      __builtin_amdgcn_s_setprio(1);
#pragma unroll
      for (int kk = 0; kk < 4; kk++)
#pragma unroll
        for (int nt = 0; nt < 4; nt++) {
          int row = nt * 16 + lrow;
          bf16x8 bk = *(const bf16x8*)&Ks[cur][row * 128 + ((kk * 4 + quad) ^ (row & 7)) * 8];
          St[nt] = __builtin_amdgcn_mfma_f32_16x16x32_bf16(bk, aq[kk], St[nt], 0, 0, 0);
        }
      __builtin_amdgcn_s_setprio(0);

      if (kt == qt) {  // diagonal: causal mask (in-tile indices, tiles aligned)
#pragma unroll
        for (int nt = 0; nt < 4; nt++)
#pragma unroll
          for (int r = 0; r < 4; r++) {
            int kj = nt * 16 + quad * 4 + r;
            if (kj > qrow) St[nt][r] = BIG_NEG;
          }
      }

      // lane-local online softmax (exp2 domain), defer-max rescale (THR=8)
      float mx = St[0][0];
#pragma unroll
      for (int nt = 0; nt < 4; nt++)
#pragma unroll
        for (int r = 0; r < 4; r++) mx = fmaxf(mx, St[nt][r]);
      mx = fmaxf(mx, __shfl_xor(mx, 16));
      mx = fmaxf(mx, __shfl_xor(mx, 32));
      if (!__all(mx <= mI + 8.0f)) {
        float mNew = fmaxf(mI, mx);
        float alpha = exp2f(mI - mNew);
        mI = mNew;
#pragma unroll
        for (int n2 = 0; n2 < 8; n2++) O[n2] *= alpha;
        Ol *= alpha;
      }
#pragma unroll
      for (int nt = 0; nt < 4; nt++)
#pragma unroll
        for (int r = 0; r < 4; r++) St[nt][r] = exp2f(St[nt][r] - mI);

      // P repack: write lane's 16 values (k = nt*16+quad*4+r) as 8 packed u32
      // into the wave-private strip; bijective swizzle of (q, kw). bit4 from
      // kw bit2 (quad-dependent for BOTH write kw=nt*8+quad*2+hh and read
      // kw=kk*16+quad*4+j2 patterns) -> 2-way on both sides (free).
#pragma unroll
      for (int nt = 0; nt < 4; nt++)
#pragma unroll
        for (int hh2 = 0; hh2 < 2; hh2++) {
          int kw = nt * 8 + quad * 2 + hh2;
          Psw[qrow * 32 + (kw ^ lrow ^ (((kw >> 2) & 1) << 4))] =
              pack2bf(St[nt][2 * hh2], St[nt][2 * hh2 + 1]);
        }

      __syncthreads();  // drains V(kt) (+K(kt+1)); Vs ready

      // O^T += (P V)^T via swapped operands: V-frag (A) reads same bytes as
      // before; P-frag (B) = lane holds P[q=lane&15][k = kk*32+quad*8+j].
#pragma unroll
      for (int kk = 0; kk < 2; kk++) {
        union { unsigned u[4]; bf16x8 v; } bp;
#pragma unroll
        for (int j2 = 0; j2 < 4; j2++) {
          int kw = kk * 16 + quad * 4 + j2;
          bp.u[j2] = Psw[qrow * 32 + (kw ^ lrow ^ (((kw >> 2) & 1) << 4))];
        }
        __builtin_amdgcn_s_setprio(1);
#pragma unroll
        for (int n2 = 0; n2 < 8; n2++) {
          int row = n2 * 16 + lrow;
          bf16x8 bv = *(const bf16x8*)&Vs[row * 64 + ((kk * 4 + quad) ^ (row & 7)) * 8];
          O[n2] = __builtin_amdgcn_mfma_f32_16x16x32_bf16(bv, bp.v, O[n2], 0, 0, 0);
        }
        Ol = __builtin_amdgcn_mfma_f32_16x16x32_bf16(vones, bp.v, Ol, 0, 0, 0);
        __builtin_amdgcn_s_setprio(0);
      }
    }

    // epilogue: lane owns q = q0 + qrow; d = n2*16 + quad*4 + r
    float il = 1.0f / Ol[0];
    short* yrow = yb + (size_t)(b * SEQ + q0 + qrow) * DIMN + h * HD;
#pragma unroll
    for (int n2 = 0; n2 < 8; n2++) {
      short o[4];
#pragma unroll
      for (int r = 0; r < 4; r++) o[r] = bf16rn(O[n2][r] * il);
      *(uint2*)&yrow[n2 * 16 + quad * 4] = *(const uint2*)o;
    }
  }
}

// ----------------------------------------------------------------- launch
extern "C" void kernel_launch(void* const* d_in, const int* in_sizes, int n_in,
                              void* d_out, int out_size, void* d_ws, size_t ws_size,
                              hipStream_t stream) {
  const float* x      = (const float*)d_in[0];
  const float* q_gain = (const float*)d_in[1];
  const float* W_q    = (const float*)d_in[2];
  const float* W_k    = (const float*)d_in[3];
  const float* W_v    = (const float*)d_in[4];
  const float* W_proj = (const float*)d_in[5];
  float* out = (float*)d_out;
  char* ws = (char*)d_ws;

  short* xb    = (short*)(ws);                // MROWS*DIMN bf16   16.78 MB
  short* wqkv  = (short*)(ws + 16777216);     // NQKV*DIMN bf16    12.58 MB
  short* wproj = (short*)(ws + 29360128);     // DIMN*DIMN bf16     8.39 MB
  short* qkvb  = (short*)(ws + 37748736);     // MROWS*NQKV bf16   25.17 MB
  short* q     = (short*)(ws + 62914560);     // MROWS*DIMN bf16   16.78 MB
  short* k     = (short*)(ws + 79691776);     // MROWS*KVD bf16     4.19 MB
  short* vT    = (short*)(ws + 83886080);     // transposed V bf16  4.19 MB
  short* y     = xb;                          // alias: xb dead after QKV GEMM
  float2* tab  = (float2*)xb;                 // alias: rope table in dead xb

  auto cvt = [&](const float* src, short* dst, int n) {
    int n8 = n / 8;
    f32_to_bf16_kern<<<(n8 + 255) / 256, 256, 0, stream>>>(src, dst, n8);
  };
  cvt(x, xb, MROWS * DIMN);
  cvt(W_q, wqkv, DIMN * DIMN);
  cvt(W_k, wqkv + DIMN * DIMN, KVD * DIMN);
  cvt(W_v, wqkv + DIMN * DIMN + KVD * DIMN, KVD * DIMN);
  cvt(W_proj, wproj, DIMN * DIMN);

  // qkv (bf16) = x @ [Wq;Wk;Wv]^T
  gemm_bt_as<short><<<dim3(NQKV / 128, MROWS / 128), 256, 0, stream>>>(xb, wqkv, qkvb, NQKV, DIMN);
  // rope table into (now dead) xb region, then norm+rope
  rope_tab_kern<<<(SEQ * 64) / 256, 256, 0, stream>>>(tab);
  rms_rope_kern<<<(MROWS * 20) / 4, 256, 0, stream>>>(qkvb, q_gain, tab, q, k);
  vT_kern<<<dim3(SEQ / 64, HD / 64, BATCH * NKVH), 256, 0, stream>>>(qkvb, vT);
  attn_kern<<<dim3(16, 32), 256, 0, stream>>>(q, k, vT, y);
  // out (f32) = y @ Wproj^T
  gemm_bt_as<float><<<dim3(DIMN / 128, MROWS / 128), 256, 0, stream>>>(y, wproj, out, DIMN, DIMN);
}